// Round 1
// baseline (681.313 us; speedup 1.0000x reference)
//
#include <hip/hip_runtime.h>
#include <hip/hip_bf16.h>

#define NPTS 32768
#define KNN 20
#define NN 4096

__device__ __forceinline__ float lrelu(float x){ return x >= 0.f ? x : 0.2f*x; }

// ---------------- K0: transpose + q_pre/p_pre + stats ----------------
__global__ void __launch_bounds__(256) k0_prep(
    const float* __restrict__ pts, const float* __restrict__ feat,
    const float* __restrict__ wq, const float* __restrict__ wpos1,
    float* __restrict__ ft, float* __restrict__ pt4,
    float* __restrict__ qp, float* __restrict__ pp,
    float* __restrict__ qsum, float* __restrict__ qsq,
    float* __restrict__ psum, float* __restrict__ psq)
{
    __shared__ float swq[2048];
    __shared__ float red[4][64];
    __shared__ float red2[4][64];
    int tid = threadIdx.x;
    for (int m = tid; m < 2048; m += 256) swq[m] = wq[m];
    __syncthreads();
    int r = blockIdx.x * 256 + tid;
    int b = r >> 12, n = r & 4095;
    float p0 = pts[(size_t)(b*3+0)*NN + n];
    float p1 = pts[(size_t)(b*3+1)*NN + n];
    float p2 = pts[(size_t)(b*3+2)*NN + n];
    float pm = (p0+p1+p2) * (1.f/3.f);
    *(float4*)(pt4 + (size_t)r*4) = make_float4(p0,p1,p2,pm);
    float f[32];
    #pragma unroll
    for (int c=0;c<32;c++) f[c] = feat[((size_t)b*32+c)*NN + n];
    #pragma unroll
    for (int c=0;c<32;c+=4)
        *(float4*)(ft + (size_t)r*32 + c) = make_float4(f[c],f[c+1],f[c+2],f[c+3]);
    float q[64];
    for (int o=0;o<64;o++){
        float a = 0.f;
        #pragma unroll
        for (int c=0;c<32;c++) a += swq[o*32+c]*f[c];
        q[o] = a;
    }
    for (int o=0;o<64;o+=4)
        *(float4*)(qp + (size_t)r*64 + o) = make_float4(q[o],q[o+1],q[o+2],q[o+3]);
    float pr[8];
    #pragma unroll
    for (int o=0;o<6;o++) pr[o] = wpos1[o*3+0]*p0 + wpos1[o*3+1]*p1 + wpos1[o*3+2]*p2;
    pr[6]=0.f; pr[7]=0.f;
    *(float4*)(pp + (size_t)r*8 + 0) = make_float4(pr[0],pr[1],pr[2],pr[3]);
    *(float4*)(pp + (size_t)r*8 + 4) = make_float4(pr[4],pr[5],pr[6],pr[7]);
    int lane = tid & 63, wv = tid >> 6;
    for (int o=0;o<64;o++){
        float s = q[o], s2 = q[o]*q[o];
        for (int d=1; d<64; d<<=1){ s += __shfl_xor(s,d); s2 += __shfl_xor(s2,d); }
        if (lane==0){ red[wv][o]=s; red2[wv][o]=s2; }
    }
    __syncthreads();
    if (tid < 64){
        atomicAdd(qsum+tid, red[0][tid]+red[1][tid]+red[2][tid]+red[3][tid]);
        atomicAdd(qsq +tid, red2[0][tid]+red2[1][tid]+red2[2][tid]+red2[3][tid]);
    }
    __syncthreads();
    for (int o=0;o<6;o++){
        float s = pr[o], s2 = pr[o]*pr[o];
        for (int d=1; d<64; d<<=1){ s += __shfl_xor(s,d); s2 += __shfl_xor(s2,d); }
        if (lane==0){ red[wv][o]=s; red2[wv][o]=s2; }
    }
    __syncthreads();
    if (tid < 6){
        atomicAdd(psum+tid, red[0][tid]+red[1][tid]+red[2][tid]+red[3][tid]);
        atomicAdd(psq +tid, red2[0][tid]+red2[1][tid]+red2[2][tid]+red2[3][tid]);
    }
}

// ---------------- K1: bnq / bnp params ----------------
__global__ void k1_paramsA(
    const float* __restrict__ qsum, const float* __restrict__ qsq,
    const float* __restrict__ psum, const float* __restrict__ psq,
    const float* __restrict__ gq, const float* __restrict__ bq,
    const float* __restrict__ gp, const float* __restrict__ bp,
    float* __restrict__ bnq_a, float* __restrict__ bnq_c,
    float* __restrict__ bnp_a, float* __restrict__ bnp_c)
{
    int t = threadIdx.x;
    const float inv = 1.f/32768.f;
    if (t < 64){
        float m = qsum[t]*inv; float v = qsq[t]*inv - m*m;
        float a = gq[t]*rsqrtf(v + 1e-5f);
        bnq_a[t] = a; bnq_c[t] = bq[t] - m*a;
    }
    if (t < 6){
        float m = psum[t]*inv; float v = psq[t]*inv - m*m;
        float a = gp[t]*rsqrtf(v + 1e-5f);
        bnp_a[t] = a; bnp_c[t] = bp[t] - m*a;
    }
}

// ---------------- K2: main fused attention per point ----------------
__global__ void __launch_bounds__(64) k2_main(
    const float* __restrict__ ft, const float* __restrict__ pt4,
    const float* __restrict__ qp, const float* __restrict__ pp,
    const int* __restrict__ idx,
    const float* __restrict__ wefp, const float* __restrict__ weff,
    const float* __restrict__ wpos2, const float* __restrict__ wattn,
    const float* __restrict__ wres,
    const float* __restrict__ bnq_a, const float* __restrict__ bnq_c,
    const float* __restrict__ bnp_a, const float* __restrict__ bnp_c,
    __hip_bfloat16* __restrict__ yv, __hip_bfloat16* __restrict__ rf,
    float* __restrict__ yslot, float* __restrict__ rslot)
{
    __shared__ __align__(16) float snbf[KNN][32];
    __shared__ float4 snbp[KNN];
    __shared__ __align__(16) float sattn[KNN][64];
    __shared__ __align__(16) float skf[KNN][64];
    __shared__ __align__(16) float sattn2[KNN][96];
    __shared__ float skp[6][KNN];
    __shared__ float sfc[32];
    __shared__ float sfm[KNN];
    __shared__ float spos[6];
    __shared__ int sidx[KNN];

    const int c = threadIdx.x;
    const int r = blockIdx.x;

    if (c < 32) sfc[c] = ft[(size_t)r*32 + c];
    if (c < KNN) sidx[c] = idx[(size_t)r*KNN + c];
    float xq = lrelu(bnq_a[c]*qp[(size_t)r*64 + c] + bnq_c[c]);
    if (c < 6) spos[c] = lrelu(bnp_a[c]*pp[(size_t)r*8 + c] + bnp_c[c]);
    __syncthreads();

    for (int m=c; m<KNN*8; m+=64){
        int k = m >> 3, qq = m & 7;
        ((float4*)&snbf[k][0])[qq] = *(const float4*)(ft + (size_t)sidx[k]*32 + qq*4);
    }
    if (c < KNN) snbp[c] = *(const float4*)(pt4 + (size_t)sidx[c]*4);
    __syncthreads();

    if (c < KNN){
        float s = 0.f;
        #pragma unroll
        for (int j=0;j<32;j++) s += snbf[c][j];
        sfm[c] = s * (1.f/32.f);
    }
    if (c < 6){
        const float* w = wefp + c*7;
        float4 pc = *(const float4*)(pt4 + (size_t)r*4);
        float base = pc.x*(w[4]-w[0]) + pc.y*(w[5]-w[1]) + pc.z*(w[6]-w[2]);
        for (int k=0;k<KNN;k++){
            float4 nb = snbp[k];
            skp[c][k] = base + w[0]*nb.x + w[1]*nb.y + w[2]*nb.z + w[3]*nb.w;
        }
    }
    __syncthreads();

    // knn_feat channel c, all k
    float kf[KNN];
    {
        const float* w = weff + (size_t)c*65;
        float base = 0.f;
        #pragma unroll
        for (int j=0;j<32;j++) base += sfc[j]*(w[33+j]-w[j]);
        float w32 = w[32];
        #pragma unroll
        for (int k=0;k<KNN;k++) kf[k] = base + w32*sfm[k];
        #pragma unroll
        for (int j=0;j<32;j+=4){
            float4 wv = *(const float4*)(w + j);
            #pragma unroll
            for (int k=0;k<KNN;k++){
                float4 fv = *(const float4*)(&snbf[k][j]);
                kf[k] += wv.x*fv.x + wv.y*fv.y + wv.z*fv.z + wv.w*fv.w;
            }
        }
        #pragma unroll
        for (int k=0;k<KNN;k++) skf[k][c] = kf[k];
    }
    // pos2 + attn + softmax over k (channel c)
    {
        float w6[6];
        #pragma unroll
        for (int j=0;j<6;j++) w6[j] = wpos2[c*6+j];
        float a[KNN]; float mx = -1e30f;
        #pragma unroll
        for (int k=0;k<KNN;k++){
            float pos = 0.f;
            #pragma unroll
            for (int j=0;j<6;j++) pos += (spos[j]-skp[j][k])*w6[j];
            float v = (xq - kf[k] + pos)*0.125f;
            a[k] = v; mx = fmaxf(mx, v);
        }
        float s = 0.f;
        #pragma unroll
        for (int k=0;k<KNN;k++){ a[k] = __expf(a[k]-mx); s += a[k]; }
        float inv = 1.f/s;
        #pragma unroll
        for (int k=0;k<KNN;k++) sattn[k][c] = a[k]*inv;
    }
    __syncthreads();

    // attn2 = attn * w_attn^T : outputs c and 64+(c&31)
    {
        float acc[KNN], accb[KNN];
        #pragma unroll
        for (int k=0;k<KNN;k++){ acc[k]=0.f; accb[k]=0.f; }
        const float* wa0 = wattn + (size_t)c*64;
        const float* wa1 = wattn + (size_t)(64 + (c&31))*64;
        for (int j=0;j<64;j+=4){
            float4 w0 = *(const float4*)(wa0+j);
            float4 w1 = *(const float4*)(wa1+j);
            #pragma unroll
            for (int k=0;k<KNN;k++){
                float4 av = *(const float4*)(&sattn[k][j]);
                acc[k]  += w0.x*av.x + w0.y*av.y + w0.z*av.z + w0.w*av.w;
                accb[k] += w1.x*av.x + w1.y*av.y + w1.z*av.z + w1.w*av.w;
            }
        }
        #pragma unroll
        for (int k=0;k<KNN;k++) sattn2[k][c] = acc[k];
        if (c < 32){
            #pragma unroll
            for (int k=0;k<KNN;k++) sattn2[k][64+c] = accb[k];
        }
    }
    __syncthreads();

    // y[h][k] for h = c < 16
    if (c < 16){
        float sum=0.f, sq=0.f;
        for (int k=0;k<KNN;k++){
            float v = 0.f;
            #pragma unroll
            for (int j=0;j<6;j++) v += sattn2[k][c*6+j]*skp[j][k];
            yv[(size_t)r*320 + c*KNN + k] = __float2bfloat16(v);
            sum += v; sq += v*v;
        }
        atomicAdd(yslot + (size_t)(r&255)*32 + c, sum);
        atomicAdd(yslot + (size_t)(r&255)*32 + 16 + c, sq);
    }
    // rf (res pre-bn) channel c
    {
        float acc[KNN];
        #pragma unroll
        for (int k=0;k<KNN;k++) acc[k]=0.f;
        const float* w = wres + (size_t)c*64;
        for (int j=0;j<64;j+=4){
            float4 wv = *(const float4*)(w+j);
            #pragma unroll
            for (int k=0;k<KNN;k++){
                float4 fv = *(const float4*)(&skf[k][j]);
                acc[k] += wv.x*fv.x + wv.y*fv.y + wv.z*fv.z + wv.w*fv.w;
            }
        }
        float sum=0.f, sq=0.f;
        #pragma unroll
        for (int k=0;k<KNN;k++){
            rf[(size_t)r*1280 + k*64 + c] = __float2bfloat16(acc[k]);
            sum += acc[k]; sq += acc[k]*acc[k];
        }
        atomicAdd(rslot + (size_t)(r&255)*128 + c, sum);
        atomicAdd(rslot + (size_t)(r&255)*128 + 64 + c, sq);
    }
}

// ---------------- K3: bn1 (y) + bnres params ----------------
__global__ void k3_paramsB(
    const float* __restrict__ yslot, const float* __restrict__ rslot,
    const float* __restrict__ g1, const float* __restrict__ b1,
    const float* __restrict__ gr, const float* __restrict__ br,
    float* __restrict__ bn1_a, float* __restrict__ bn1_c,
    float* __restrict__ bnr_a, float* __restrict__ bnr_c)
{
    __shared__ float sy[32];
    __shared__ float sr[128];
    int t = threadIdx.x; // 128
    float s1 = 0.f;
    if (t < 32){ for (int i=0;i<256;i++) s1 += yslot[(size_t)i*32+t]; }
    float s2 = 0.f;
    for (int i=0;i<256;i++) s2 += rslot[(size_t)i*128+t];
    if (t < 32) sy[t] = s1;
    sr[t] = s2;
    __syncthreads();
    const float inv = 1.f/655360.f;
    if (t < 16){
        float m = sy[t]*inv; float v = sy[16+t]*inv - m*m;
        float a = g1[t]*rsqrtf(v + 1e-5f);
        bn1_a[t] = a; bn1_c[t] = b1[t] - m*a;
    }
    if (t < 64){
        float m = sr[t]*inv; float v = sr[64+t]*inv - m*m;
        float a = gr[t]*rsqrtf(v + 1e-5f);
        bnr_a[t] = a; bnr_c[t] = br[t] - m*a;
    }
}

// ---------------- K4: lin (y2 * w_lin) stats ----------------
__global__ void __launch_bounds__(64) k4_linstats(
    const __hip_bfloat16* __restrict__ yv,
    const float* __restrict__ bn1_a, const float* __restrict__ bn1_c,
    const float* __restrict__ wl, float* __restrict__ lslot)
{
    __shared__ float sy2[16*KNN];
    const int c = threadIdx.x;
    float wlr[16];
    #pragma unroll
    for (int h=0;h<16;h++) wlr[h] = wl[c*16+h];
    float lsum=0.f, lsq=0.f;
    for (int i=0;i<16;i++){
        size_t r = (size_t)blockIdx.x*16 + i;
        __syncthreads();
        for (int m=c; m<320; m+=64){
            float yy = __bfloat162float(yv[r*320+m]);
            int h = m/KNN;
            sy2[m] = lrelu(bn1_a[h]*yy + bn1_c[h]);
        }
        __syncthreads();
        for (int k=0;k<KNN;k++){
            float lv = 0.f;
            #pragma unroll
            for (int h=0;h<16;h++) lv += wlr[h]*sy2[h*KNN+k];
            lsum += lv; lsq += lv*lv;
        }
    }
    atomicAdd(lslot + (size_t)(blockIdx.x&255)*128 + c, lsum);
    atomicAdd(lslot + (size_t)(blockIdx.x&255)*128 + 64 + c, lsq);
}

// ---------------- K5: bnlin params ----------------
__global__ void k5_paramsC(
    const float* __restrict__ lslot,
    const float* __restrict__ gl, const float* __restrict__ bl,
    float* __restrict__ bnl_a, float* __restrict__ bnl_c)
{
    __shared__ float sr[128];
    int t = threadIdx.x; // 128
    float s = 0.f;
    for (int i=0;i<256;i++) s += lslot[(size_t)i*128+t];
    sr[t] = s;
    __syncthreads();
    const float inv = 1.f/655360.f;
    if (t < 64){
        float m = sr[t]*inv; float v = sr[64+t]*inv - m*m;
        float a = gl[t]*rsqrtf(v + 1e-5f);
        bnl_a[t] = a; bnl_c[t] = bl[t] - m*a;
    }
}

// ---------------- K6: final combine + max over k ----------------
__global__ void __launch_bounds__(256) k6_final(
    const __hip_bfloat16* __restrict__ yv, const __hip_bfloat16* __restrict__ rf,
    const float* __restrict__ bn1_a, const float* __restrict__ bn1_c,
    const float* __restrict__ wl,
    const float* __restrict__ bnl_a, const float* __restrict__ bnl_c,
    const float* __restrict__ bnr_a, const float* __restrict__ bnr_c,
    float* __restrict__ out)
{
    __shared__ float sy2[4][16*KNN];
    __shared__ float sout[64][17];
    const int tid = threadIdx.x;
    const int w = tid >> 6, o = tid & 63;
    float wlr[16];
    #pragma unroll
    for (int h=0;h<16;h++) wlr[h] = wl[o*16+h];
    const float la = bnl_a[o], lc = bnl_c[o];
    const float ra = bnr_a[o], rc = bnr_c[o];
    const int r0 = blockIdx.x*16;
    for (int i=0;i<4;i++){
        const size_t r = (size_t)r0 + w*4 + i;
        __syncthreads();
        for (int m=o;m<320;m+=64){
            float yy = __bfloat162float(yv[r*320+m]);
            int h = m/KNN;
            sy2[w][m] = lrelu(bn1_a[h]*yy + bn1_c[h]);
        }
        __syncthreads();
        float best = -1e30f;
        for (int k=0;k<KNN;k++){
            float rv = __bfloat162float(rf[r*1280 + k*64 + o]);
            float lv = 0.f;
            #pragma unroll
            for (int h=0;h<16;h++) lv += wlr[h]*sy2[w][h*KNN+k];
            float val = lrelu(la*lv + lc + ra*rv + rc);
            best = fmaxf(best, val);
        }
        sout[o][w*4+i] = best;
    }
    __syncthreads();
    const int b = r0 >> 12, n0 = r0 & 4095;
    for (int m=tid;m<1024;m+=256){
        int oo = m >> 4, ii = m & 15;
        out[((size_t)b*64+oo)*NN + n0 + ii] = sout[oo][ii];
    }
}

extern "C" void kernel_launch(void* const* d_in, const int* in_sizes, int n_in,
                              void* d_out, int out_size, void* d_ws, size_t ws_size,
                              hipStream_t stream)
{
    const float* pts   = (const float*)d_in[0];
    const float* feat  = (const float*)d_in[1];
    const int*   idx   = (const int*)d_in[2];
    const float* wefp  = (const float*)d_in[3];
    const float* weff  = (const float*)d_in[4];
    const float* wq    = (const float*)d_in[5];
    const float* gq    = (const float*)d_in[6];
    const float* bq    = (const float*)d_in[7];
    const float* wpos1 = (const float*)d_in[8];
    const float* gp    = (const float*)d_in[9];
    const float* bp    = (const float*)d_in[10];
    const float* wpos2 = (const float*)d_in[11];
    const float* wattn = (const float*)d_in[12];
    const float* g1    = (const float*)d_in[13];
    const float* b1    = (const float*)d_in[14];
    const float* wl    = (const float*)d_in[15];
    const float* gl    = (const float*)d_in[16];
    const float* bl    = (const float*)d_in[17];
    const float* wres  = (const float*)d_in[18];
    const float* gr    = (const float*)d_in[19];
    const float* br    = (const float*)d_in[20];
    float* out = (float*)d_out;

    char* ws = (char*)d_ws;
    size_t o_ft = 0;
    size_t o_pt = o_ft + (size_t)NPTS*32*4;
    size_t o_qp = o_pt + (size_t)NPTS*4*4;
    size_t o_pp = o_qp + (size_t)NPTS*64*4;
    size_t o_st = o_pp + (size_t)NPTS*8*4;
    size_t o_qsum  = o_st;
    size_t o_qsq   = o_qsum + 64*4;
    size_t o_psum  = o_qsq  + 64*4;
    size_t o_psq   = o_psum + 8*4;
    size_t o_yslot = o_psq  + 8*4;
    size_t o_rslot = o_yslot + (size_t)256*32*4;
    size_t o_lslot = o_rslot + (size_t)256*128*4;
    size_t zero_bytes = (o_lslot + (size_t)256*128*4) - o_st;
    size_t o_par   = o_st + zero_bytes;
    size_t o_bnq_a = o_par;
    size_t o_bnq_c = o_bnq_a + 64*4;
    size_t o_bnp_a = o_bnq_c + 64*4;
    size_t o_bnp_c = o_bnp_a + 8*4;
    size_t o_bn1_a = o_bnp_c + 8*4;
    size_t o_bn1_c = o_bn1_a + 16*4;
    size_t o_bnl_a = o_bn1_c + 16*4;
    size_t o_bnl_c = o_bnl_a + 64*4;
    size_t o_bnr_a = o_bnl_c + 64*4;
    size_t o_bnr_c = o_bnr_a + 64*4;
    size_t o_yv = (o_bnr_c + 64*4 + 255) & ~(size_t)255;
    size_t o_rf = o_yv + (size_t)NPTS*320*2;

    float* ftp  = (float*)(ws + o_ft);
    float* pt4  = (float*)(ws + o_pt);
    float* qpb  = (float*)(ws + o_qp);
    float* ppb  = (float*)(ws + o_pp);
    float* qsum = (float*)(ws + o_qsum);
    float* qsq  = (float*)(ws + o_qsq);
    float* psum = (float*)(ws + o_psum);
    float* psq  = (float*)(ws + o_psq);
    float* yslot= (float*)(ws + o_yslot);
    float* rslot= (float*)(ws + o_rslot);
    float* lslot= (float*)(ws + o_lslot);
    float* bnq_a= (float*)(ws + o_bnq_a);
    float* bnq_c= (float*)(ws + o_bnq_c);
    float* bnp_a= (float*)(ws + o_bnp_a);
    float* bnp_c= (float*)(ws + o_bnp_c);
    float* bn1_a= (float*)(ws + o_bn1_a);
    float* bn1_c= (float*)(ws + o_bn1_c);
    float* bnl_a= (float*)(ws + o_bnl_a);
    float* bnl_c= (float*)(ws + o_bnl_c);
    float* bnr_a= (float*)(ws + o_bnr_a);
    float* bnr_c= (float*)(ws + o_bnr_c);
    __hip_bfloat16* yvp = (__hip_bfloat16*)(ws + o_yv);
    __hip_bfloat16* rfp = (__hip_bfloat16*)(ws + o_rf);

    hipMemsetAsync(ws + o_st, 0, zero_bytes, stream);

    k0_prep<<<128, 256, 0, stream>>>(pts, feat, wq, wpos1, ftp, pt4, qpb, ppb,
                                     qsum, qsq, psum, psq);
    k1_paramsA<<<1, 64, 0, stream>>>(qsum, qsq, psum, psq, gq, bq, gp, bp,
                                     bnq_a, bnq_c, bnp_a, bnp_c);
    k2_main<<<NPTS, 64, 0, stream>>>(ftp, pt4, qpb, ppb, idx,
                                     wefp, weff, wpos2, wattn, wres,
                                     bnq_a, bnq_c, bnp_a, bnp_c,
                                     yvp, rfp, yslot, rslot);
    k3_paramsB<<<1, 128, 0, stream>>>(yslot, rslot, g1, b1, gr, br,
                                      bn1_a, bn1_c, bnr_a, bnr_c);
    k4_linstats<<<2048, 64, 0, stream>>>(yvp, bn1_a, bn1_c, wl, lslot);
    k5_paramsC<<<1, 128, 0, stream>>>(lslot, gl, bl, bnl_a, bnl_c);
    k6_final<<<2048, 256, 0, stream>>>(yvp, rfp, bn1_a, bn1_c, wl,
                                       bnl_a, bnl_c, bnr_a, bnr_c, out);
}

// Round 2
// 537.395 us; speedup vs baseline: 1.2678x; 1.2678x over previous
//
#include <hip/hip_runtime.h>

#define KNN 20
#define NN 4096
#define NPTS 32768
#define PPW 8

using short8 = __attribute__((ext_vector_type(8))) short;
using f32x4v = __attribute__((ext_vector_type(4))) float;

__device__ __forceinline__ float lrelu(float x){ return x >= 0.f ? x : 0.2f*x; }
__device__ __forceinline__ unsigned short f2b(float x){
    union { float f; unsigned u; } v; v.f = x;
    unsigned r = v.u + 0x7FFFu + ((v.u >> 16) & 1u);
    return (unsigned short)(r >> 16);
}
__device__ __forceinline__ float b2f(unsigned h){
    union { unsigned u; float f; } v; v.u = h << 16; return v.f;
}
#define WSYNC() do { asm volatile("s_waitcnt lgkmcnt(0)" ::: "memory"); __builtin_amdgcn_sched_barrier(0); } while(0)

// ---------------- kprep: pack weight fragments + wdiff/w32 ----------------
// B-frag for mfma_f32_16x16x32_bf16: lane l holds B[k][n], n = nt*16+(l&15),
// k = koff + (j>=4?16:0) + 4*(l>>4) + (j&3), j = 0..7.
__global__ void kprep(const float* __restrict__ weff, const float* __restrict__ wattn,
                      const float* __restrict__ wres,
                      unsigned short* __restrict__ packW, float* __restrict__ wdiff,
                      float* __restrict__ w32t)
{
    int t = threadIdx.x;
    for (int q = t; q < 1536; q += 256){
        int f = q >> 6, l = q & 63;
        const float* W; int n, rowlen, koff;
        if (f < 4){ W = weff; rowlen = 65; n = f*16 + (l&15); koff = 0; }
        else if (f < 16){ W = wattn; rowlen = 64; int ff = f-4; n = (ff>>1)*16 + (l&15); koff = (ff&1)*32; }
        else { W = wres; rowlen = 64; int ff = f-16; n = (ff>>1)*16 + (l&15); koff = (ff&1)*32; }
        #pragma unroll
        for (int j=0;j<8;j++){
            int k = koff + (j>=4?16:0) + 4*(l>>4) + (j&3);
            packW[(size_t)(f*64+l)*8 + j] = f2b(W[n*rowlen + k]);
        }
    }
    for (int q = t; q < 2048; q += 256){
        int c = q >> 5, j = q & 31;
        wdiff[q] = weff[c*65 + 33 + j] - weff[c*65 + j];
    }
    if (t < 64) w32t[t] = weff[t*65 + 32];
}

// ---------------- K0: tables + q/base GEMV + stats ----------------
__global__ void __launch_bounds__(256) k0_prep(
    const float* __restrict__ pts, const float* __restrict__ feat,
    const float* __restrict__ wq, const float* __restrict__ wpos1,
    const float* __restrict__ wefp, const float* __restrict__ wdiff,
    unsigned short* __restrict__ ft16, float* __restrict__ pt4,
    unsigned short* __restrict__ qp16, float* __restrict__ pp,
    unsigned short* __restrict__ base16, float* __restrict__ bpp,
    float* __restrict__ qsum, float* __restrict__ qsq,
    float* __restrict__ psum, float* __restrict__ psq)
{
    __shared__ float swq[2048];
    __shared__ float swd[2048];
    __shared__ float red[4][64], red2[4][64];
    int tid = threadIdx.x;
    for (int m=tid;m<2048;m+=256){ swq[m]=wq[m]; swd[m]=wdiff[m]; }
    __syncthreads();
    int r = blockIdx.x*256 + tid;
    int b = r >> 12, n = r & 4095;
    float p0 = pts[((size_t)b*3+0)*NN+n];
    float p1 = pts[((size_t)b*3+1)*NN+n];
    float p2 = pts[((size_t)b*3+2)*NN+n];
    float pm = (p0+p1+p2)*(1.f/3.f);
    *(float4*)(pt4 + (size_t)r*4) = make_float4(p0,p1,p2,pm);
    float f[32];
    #pragma unroll
    for (int c=0;c<32;c++) f[c] = feat[((size_t)b*32+c)*NN+n];
    #pragma unroll
    for (int c=0;c<32;c+=2){
        unsigned pk = (unsigned)f2b(f[c]) | ((unsigned)f2b(f[c+1])<<16);
        *(unsigned*)(ft16 + (size_t)r*32 + c) = pk;
    }
    float q[64];
    for (int o=0;o<64;o++){
        float a=0.f;
        #pragma unroll
        for (int c=0;c<32;c++) a += swq[o*32+c]*f[c];
        q[o]=a;
    }
    for (int o=0;o<64;o+=2){
        unsigned pk = (unsigned)f2b(q[o]) | ((unsigned)f2b(q[o+1])<<16);
        *(unsigned*)(qp16 + (size_t)r*64 + o) = pk;
    }
    int lane = tid & 63, wvv = tid>>6;
    for (int o=0;o<64;o++){
        float s=q[o], s2=q[o]*q[o];
        for (int d=1; d<64; d<<=1){ s += __shfl_xor(s,d); s2 += __shfl_xor(s2,d); }
        if (lane==0){ red[wvv][o]=s; red2[wvv][o]=s2; }
    }
    __syncthreads();
    if (tid<64){
        atomicAdd(qsum+tid, red[0][tid]+red[1][tid]+red[2][tid]+red[3][tid]);
        atomicAdd(qsq+tid, red2[0][tid]+red2[1][tid]+red2[2][tid]+red2[3][tid]);
    }
    // base = f . wdiff^T
    for (int o=0;o<64;o++){
        float a=0.f;
        #pragma unroll
        for (int c=0;c<32;c++) a += swd[o*32+c]*f[c];
        q[o]=a;
    }
    for (int o=0;o<64;o+=2){
        unsigned pk = (unsigned)f2b(q[o]) | ((unsigned)f2b(q[o+1])<<16);
        *(unsigned*)(base16 + (size_t)r*64 + o) = pk;
    }
    float pr[8];
    #pragma unroll
    for (int o=0;o<6;o++) pr[o] = wpos1[o*3]*p0 + wpos1[o*3+1]*p1 + wpos1[o*3+2]*p2;
    pr[6]=0.f; pr[7]=0.f;
    *(float4*)(pp+(size_t)r*8)   = make_float4(pr[0],pr[1],pr[2],pr[3]);
    *(float4*)(pp+(size_t)r*8+4) = make_float4(pr[4],pr[5],pr[6],pr[7]);
    __syncthreads();
    for (int o=0;o<6;o++){
        float s=pr[o], s2=pr[o]*pr[o];
        for (int d=1;d<64;d<<=1){ s += __shfl_xor(s,d); s2 += __shfl_xor(s2,d); }
        if (lane==0){ red[wvv][o]=s; red2[wvv][o]=s2; }
    }
    __syncthreads();
    if (tid<6){
        atomicAdd(psum+tid, red[0][tid]+red[1][tid]+red[2][tid]+red[3][tid]);
        atomicAdd(psq+tid, red2[0][tid]+red2[1][tid]+red2[2][tid]+red2[3][tid]);
    }
    #pragma unroll
    for (int j=0;j<6;j++)
        bpp[(size_t)r*8+j] = p0*(wefp[j*7+4]-wefp[j*7]) + p1*(wefp[j*7+5]-wefp[j*7+1])
                           + p2*(wefp[j*7+6]-wefp[j*7+2]);
    bpp[(size_t)r*8+6]=0.f; bpp[(size_t)r*8+7]=0.f;
}

// ---------------- K1: bnq / bnp params ----------------
__global__ void k1_paramsA(
    const float* __restrict__ qsum, const float* __restrict__ qsq,
    const float* __restrict__ psum, const float* __restrict__ psq,
    const float* __restrict__ gq, const float* __restrict__ bq,
    const float* __restrict__ gp, const float* __restrict__ bp,
    float* __restrict__ bnq_a, float* __restrict__ bnq_c,
    float* __restrict__ bnp_a, float* __restrict__ bnp_c)
{
    int t = threadIdx.x;
    const float inv = 1.f/32768.f;
    if (t < 64){
        float m = qsum[t]*inv; float v = qsq[t]*inv - m*m;
        float a = gq[t]*rsqrtf(v + 1e-5f);
        bnq_a[t] = a; bnq_c[t] = bq[t] - m*a;
    }
    if (t < 6){
        float m = psum[t]*inv; float v = psq[t]*inv - m*m;
        float a = gp[t]*rsqrtf(v + 1e-5f);
        bnp_a[t] = a; bnp_c[t] = bp[t] - m*a;
    }
}

// ---------------- K2: fused attention, MFMA, wave-per-point ----------------
#define ARENA 12032
#define ANB 0
#define ATR 2048
#define KFR 6144
#define A2B 0
#define SFM 10240
#define SSKP 10368
#define SNB4 11392
#define SIDX 11904

__global__ void __launch_bounds__(256, 3) k2_main(
    const unsigned short* __restrict__ ft16, const float* __restrict__ pt4,
    const unsigned short* __restrict__ qp16, const float* __restrict__ pp,
    const unsigned short* __restrict__ base16, const float* __restrict__ bpp,
    const int* __restrict__ idx,
    const float* __restrict__ wefp, const float* __restrict__ wpos2,
    const unsigned short* __restrict__ packW, const float* __restrict__ w32t,
    const float* __restrict__ bnq_a, const float* __restrict__ bnq_c,
    const float* __restrict__ bnp_a, const float* __restrict__ bnp_c,
    unsigned short* __restrict__ yv, unsigned short* __restrict__ rf,
    float* __restrict__ yslot, float* __restrict__ rslot)
{
    __shared__ __align__(16) char smem_[4*ARENA];
    const int tid = threadIdx.x;
    const int l = tid & 63, wv = tid >> 6;
    const int lo = l & 15, g = l >> 4;
    char* S = smem_ + wv*ARENA;

    float w2r[4][6], w32r[4];
    #pragma unroll
    for (int nt=0;nt<4;nt++){
        #pragma unroll
        for (int j=0;j<6;j++) w2r[nt][j] = wpos2[(nt*16+lo)*6+j];
        w32r[nt] = w32t[nt*16+lo];
    }
    float ysum=0.f, ysq=0.f;
    float racc[4]={0.f,0.f,0.f,0.f}, rsqa[4]={0.f,0.f,0.f,0.f};

    for (int pi=0; pi<PPW; pi++){
        const int r = blockIdx.x*(4*PPW) + wv*PPW + pi;
        WSYNC();
        if (l < KNN) *(int*)(S+SIDX+l*4) = idx[(size_t)r*KNN + l];
        WSYNC();
        // gather neighbor bf16 features into fragment-ordered LDS + row means
        #pragma unroll
        for (int it=0; it<3; it++){
            int id = it*64 + l;
            int k = id >> 3, q = id & 7;
            bool act = id < 160;
            int kk = act ? k : 0;
            int gI = *(const int*)(S+SIDX+kk*4);
            uint2 v; v.x = 0u; v.y = 0u;
            if (act) v = *(const uint2*)(ft16 + (size_t)gI*32 + q*4);
            float s = b2f(v.x & 0xffffu) + b2f(v.x >> 16) + b2f(v.y & 0xffffu) + b2f(v.y >> 16);
            s += __shfl_xor(s,1); s += __shfl_xor(s,2); s += __shfl_xor(s,4);
            if (act){
                if (q == 0) *(float*)(S+SFM+k*4) = s * (1.f/32.f);
                *(uint2*)(S + ANB + (k>>4)*1024 + ((k&15) + 16*(q&3))*16 + (q>>2)*8) = v;
            }
        }
        if (l < KNN){
            int gI = *(const int*)(S+SIDX+l*4);
            *(float4*)(S+SNB4+l*16) = *(const float4*)(pt4 + (size_t)gI*4);
        }
        WSYNC();
        if (l < KNN){
            float4 nb = *(const float4*)(S+SNB4+l*16);
            #pragma unroll
            for (int j=0;j<6;j++){
                float v = bpp[(size_t)r*8+j] + wefp[j*7]*nb.x + wefp[j*7+1]*nb.y
                        + wefp[j*7+2]*nb.z + wefp[j*7+3]*nb.w;
                *(float*)(S+SSKP + (l*8+j)*4) = v;
            }
        }
        float xqv[4], basev[4];
        #pragma unroll
        for (int nt=0;nt<4;nt++){
            int c = nt*16+lo;
            xqv[nt] = lrelu(bnq_a[c]*b2f(qp16[(size_t)r*64+c]) + bnq_c[c]);
            basev[nt] = b2f(base16[(size_t)r*64+c]);
        }
        float sp[6];
        #pragma unroll
        for (int j=0;j<6;j++) sp[j] = lrelu(bnp_a[j]*pp[(size_t)r*8+j] + bnp_c[j]);
        WSYNC();
        // ---- MFMA-1: kf[k][c] = fnb . weff ----
        f32x4v C1[2][4];
        #pragma unroll
        for (int mt=0;mt<2;mt++)
            #pragma unroll
            for (int nt=0;nt<4;nt++)
                #pragma unroll
                for (int i=0;i<4;i++) C1[mt][nt][i] = 0.f;
        short8 Af[2];
        #pragma unroll
        for (int mt=0;mt<2;mt++) Af[mt] = *(const short8*)(S + ANB + mt*1024 + l*16);
        #pragma unroll
        for (int nt=0;nt<4;nt++){
            short8 Bf = *(const short8*)(packW + (size_t)(nt*64 + l)*8);
            #pragma unroll
            for (int mt=0;mt<2;mt++)
                C1[mt][nt] = __builtin_amdgcn_mfma_f32_16x16x32_bf16(Af[mt], Bf, C1[mt][nt], 0, 0, 0);
        }
        // ---- epilogue: kf frags + attn raw ----
        #pragma unroll
        for (int mt=0;mt<2;mt++){
            #pragma unroll
            for (int i=0;i<4;i++){
                int k = mt*16 + g*4 + i;
                bool valid = (k < KNN);
                int kk = valid ? k : 0;
                float fmk = *(const float*)(S+SFM+kk*4);
                float sk[6];
                #pragma unroll
                for (int j=0;j<6;j++) sk[j] = *(const float*)(S+SSKP+(kk*8+j)*4);
                #pragma unroll
                for (int nt=0;nt<4;nt++){
                    float kf = C1[mt][nt][i] + basev[nt] + w32r[nt]*fmk;
                    if (valid){
                        int fragi = mt*2 + (nt>>1);
                        int slot = (g*4+i) + 16*(lo>>2);
                        int jj = (nt&1)*4 + (lo&3);
                        *(unsigned short*)(S + KFR + fragi*1024 + slot*16 + jj*2) = f2b(kf);
                    }
                    float pos = 0.f;
                    #pragma unroll
                    for (int j=0;j<6;j++) pos += (sp[j]-sk[j])*w2r[nt][j];
                    C1[mt][nt][i] = valid ? (xqv[nt] - kf + pos)*0.125f : -1e30f;
                }
            }
        }
        // ---- softmax over k per channel (column) ----
        #pragma unroll
        for (int nt=0;nt<4;nt++){
            float mx = -1e30f;
            #pragma unroll
            for (int mt=0;mt<2;mt++)
                #pragma unroll
                for (int i=0;i<4;i++) mx = fmaxf(mx, C1[mt][nt][i]);
            mx = fmaxf(mx, __shfl_xor(mx,16));
            mx = fmaxf(mx, __shfl_xor(mx,32));
            float sm = 0.f;
            #pragma unroll
            for (int mt=0;mt<2;mt++)
                #pragma unroll
                for (int i=0;i<4;i++){ float e = __expf(C1[mt][nt][i]-mx); C1[mt][nt][i]=e; sm += e; }
            sm += __shfl_xor(sm,16);
            sm += __shfl_xor(sm,32);
            float inv = 1.f/sm;
            #pragma unroll
            for (int mt=0;mt<2;mt++)
                #pragma unroll
                for (int i=0;i<4;i++){
                    int k = mt*16 + g*4 + i;
                    if (k < KNN){
                        int fragi = mt*2 + (nt>>1);
                        int slot = (g*4+i) + 16*(lo>>2);
                        int jj = (nt&1)*4 + (lo&3);
                        *(unsigned short*)(S + ATR + fragi*1024 + slot*16 + jj*2) = f2b(C1[mt][nt][i]*inv);
                    }
                }
        }
        WSYNC();
        // ---- MFMA-2: attn2[k][o] = attn . wattn^T (96 outs) ----
        short8 Aa[2][2];
        #pragma unroll
        for (int mt=0;mt<2;mt++)
            #pragma unroll
            for (int s=0;s<2;s++) Aa[mt][s] = *(const short8*)(S + ATR + (mt*2+s)*1024 + l*16);
        f32x4v C2[2][6];
        #pragma unroll
        for (int mt=0;mt<2;mt++)
            #pragma unroll
            for (int nt=0;nt<6;nt++)
                #pragma unroll
                for (int i=0;i<4;i++) C2[mt][nt][i] = 0.f;
        #pragma unroll
        for (int nt=0;nt<6;nt++){
            #pragma unroll
            for (int s=0;s<2;s++){
                short8 Bf = *(const short8*)(packW + (size_t)((4+nt*2+s)*64 + l)*8);
                #pragma unroll
                for (int mt=0;mt<2;mt++)
                    C2[mt][nt] = __builtin_amdgcn_mfma_f32_16x16x32_bf16(Aa[mt][s], Bf, C2[mt][nt], 0, 0, 0);
            }
        }
        WSYNC();
        #pragma unroll
        for (int mt=0;mt<2;mt++)
            #pragma unroll
            for (int nt=0;nt<6;nt++)
                #pragma unroll
                for (int i=0;i<4;i++){
                    int k = mt*16 + g*4 + i;
                    if (k < KNN){
                        int o = nt*16 + lo;
                        *(unsigned short*)(S + A2B + k*192 + o*2) = f2b(C2[mt][nt][i]);
                    }
                }
        WSYNC();
        // ---- y[h][k] = sum_j attn2[k][h*6+j] * knn_p[j][k] ----
        #pragma unroll
        for (int it=0; it<5; it++){
            int kq = it*4 + g;
            const char* row = S + A2B + kq*192 + lo*12;
            unsigned d0 = *(const unsigned*)(row);
            unsigned d1 = *(const unsigned*)(row+4);
            unsigned d2 = *(const unsigned*)(row+8);
            float yval = b2f(d0&0xffffu) * (*(const float*)(S+SSKP+(kq*8+0)*4))
                       + b2f(d0>>16)    * (*(const float*)(S+SSKP+(kq*8+1)*4))
                       + b2f(d1&0xffffu)* (*(const float*)(S+SSKP+(kq*8+2)*4))
                       + b2f(d1>>16)    * (*(const float*)(S+SSKP+(kq*8+3)*4))
                       + b2f(d2&0xffffu)* (*(const float*)(S+SSKP+(kq*8+4)*4))
                       + b2f(d2>>16)    * (*(const float*)(S+SSKP+(kq*8+5)*4));
            yv[(size_t)r*320 + lo*KNN + kq] = f2b(yval);
            ysum += yval; ysq += yval*yval;
        }
        // ---- MFMA-3: rf[k][c] = kf . wres^T ----
        short8 Ak[2][2];
        #pragma unroll
        for (int mt=0;mt<2;mt++)
            #pragma unroll
            for (int s=0;s<2;s++) Ak[mt][s] = *(const short8*)(S + KFR + (mt*2+s)*1024 + l*16);
        f32x4v C3[2][4];
        #pragma unroll
        for (int mt=0;mt<2;mt++)
            #pragma unroll
            for (int nt=0;nt<4;nt++)
                #pragma unroll
                for (int i=0;i<4;i++) C3[mt][nt][i] = 0.f;
        #pragma unroll
        for (int nt=0;nt<4;nt++){
            #pragma unroll
            for (int s=0;s<2;s++){
                short8 Bf = *(const short8*)(packW + (size_t)((16+nt*2+s)*64 + l)*8);
                #pragma unroll
                for (int mt=0;mt<2;mt++)
                    C3[mt][nt] = __builtin_amdgcn_mfma_f32_16x16x32_bf16(Ak[mt][s], Bf, C3[mt][nt], 0, 0, 0);
            }
        }
        #pragma unroll
        for (int mt=0;mt<2;mt++)
            #pragma unroll
            for (int i=0;i<4;i++){
                int k = mt*16 + g*4 + i;
                if (k < KNN){
                    #pragma unroll
                    for (int nt=0;nt<4;nt++){
                        float v = C3[mt][nt][i];
                        rf[(size_t)r*1280 + k*64 + nt*16 + lo] = f2b(v);
                        racc[nt] += v; rsqa[nt] += v*v;
                    }
                }
            }
    }
    // ---- stats reduce + atomics ----
    ysum += __shfl_xor(ysum,16); ysum += __shfl_xor(ysum,32);
    ysq  += __shfl_xor(ysq,16);  ysq  += __shfl_xor(ysq,32);
    #pragma unroll
    for (int nt=0;nt<4;nt++){
        racc[nt] += __shfl_xor(racc[nt],16); racc[nt] += __shfl_xor(racc[nt],32);
        rsqa[nt] += __shfl_xor(rsqa[nt],16); rsqa[nt] += __shfl_xor(rsqa[nt],32);
    }
    int slot = (blockIdx.x*4 + wv) & 63;
    if (l < 16){
        atomicAdd(yslot + slot*32 + l, ysum);
        #pragma unroll
        for (int nt=0;nt<4;nt++) atomicAdd(rslot + slot*128 + nt*16 + l, racc[nt]);
    } else if (l < 32){
        atomicAdd(yslot + slot*32 + 16 + lo, ysq);
        #pragma unroll
        for (int nt=0;nt<4;nt++) atomicAdd(rslot + slot*128 + 64 + nt*16 + lo, rsqa[nt]);
    }
}

// ---------------- K3: bn1 (y) + bnres params ----------------
__global__ void k3_paramsB(
    const float* __restrict__ yslot, const float* __restrict__ rslot,
    const float* __restrict__ g1, const float* __restrict__ b1,
    const float* __restrict__ gr, const float* __restrict__ br,
    float* __restrict__ bn1_a, float* __restrict__ bn1_c,
    float* __restrict__ bnr_a, float* __restrict__ bnr_c)
{
    __shared__ float sy[32];
    __shared__ float sr[128];
    int t = threadIdx.x; // 128
    float s1 = 0.f;
    if (t < 32){ for (int i=0;i<64;i++) s1 += yslot[(size_t)i*32+t]; }
    float s2 = 0.f;
    for (int i=0;i<64;i++) s2 += rslot[(size_t)i*128+t];
    if (t < 32) sy[t] = s1;
    sr[t] = s2;
    __syncthreads();
    const float inv = 1.f/655360.f;
    if (t < 16){
        float m = sy[t]*inv; float v = sy[16+t]*inv - m*m;
        float a = g1[t]*rsqrtf(v + 1e-5f);
        bn1_a[t] = a; bn1_c[t] = b1[t] - m*a;
    }
    if (t < 64){
        float m = sr[t]*inv; float v = sr[64+t]*inv - m*m;
        float a = gr[t]*rsqrtf(v + 1e-5f);
        bnr_a[t] = a; bnr_c[t] = br[t] - m*a;
    }
}

// ---------------- K4: lin (y2 * w_lin) stats ----------------
__global__ void __launch_bounds__(64) k4_linstats(
    const unsigned short* __restrict__ yv,
    const float* __restrict__ bn1_a, const float* __restrict__ bn1_c,
    const float* __restrict__ wl, float* __restrict__ lslot)
{
    __shared__ float sy2[16*KNN];
    const int c = threadIdx.x;
    float wlr[16];
    #pragma unroll
    for (int h=0;h<16;h++) wlr[h] = wl[c*16+h];
    float lsum=0.f, lsq=0.f;
    for (int i=0;i<16;i++){
        size_t r = (size_t)blockIdx.x*16 + i;
        __syncthreads();
        for (int m=c; m<320; m+=64){
            float yy = b2f(yv[r*320+m]);
            int h = m/KNN;
            sy2[m] = lrelu(bn1_a[h]*yy + bn1_c[h]);
        }
        __syncthreads();
        for (int k=0;k<KNN;k++){
            float lv = 0.f;
            #pragma unroll
            for (int h=0;h<16;h++) lv += wlr[h]*sy2[h*KNN+k];
            lsum += lv; lsq += lv*lv;
        }
    }
    atomicAdd(lslot + (size_t)(blockIdx.x&255)*128 + c, lsum);
    atomicAdd(lslot + (size_t)(blockIdx.x&255)*128 + 64 + c, lsq);
}

// ---------------- K5: bnlin params ----------------
__global__ void k5_paramsC(
    const float* __restrict__ lslot,
    const float* __restrict__ gl, const float* __restrict__ bl,
    float* __restrict__ bnl_a, float* __restrict__ bnl_c)
{
    __shared__ float sr[128];
    int t = threadIdx.x; // 128
    float s = 0.f;
    for (int i=0;i<256;i++) s += lslot[(size_t)i*128+t];
    sr[t] = s;
    __syncthreads();
    const float inv = 1.f/655360.f;
    if (t < 64){
        float m = sr[t]*inv; float v = sr[64+t]*inv - m*m;
        float a = gl[t]*rsqrtf(v + 1e-5f);
        bnl_a[t] = a; bnl_c[t] = bl[t] - m*a;
    }
}

// ---------------- K6: final combine + max over k ----------------
__global__ void __launch_bounds__(256) k6_final(
    const unsigned short* __restrict__ yv, const unsigned short* __restrict__ rf,
    const float* __restrict__ bn1_a, const float* __restrict__ bn1_c,
    const float* __restrict__ wl,
    const float* __restrict__ bnl_a, const float* __restrict__ bnl_c,
    const float* __restrict__ bnr_a, const float* __restrict__ bnr_c,
    float* __restrict__ out)
{
    __shared__ float sy2[4][16*KNN];
    __shared__ float sout[64][17];
    const int tid = threadIdx.x;
    const int w = tid >> 6, o = tid & 63;
    float wlr[16];
    #pragma unroll
    for (int h=0;h<16;h++) wlr[h] = wl[o*16+h];
    const float la = bnl_a[o], lc = bnl_c[o];
    const float ra = bnr_a[o], rc = bnr_c[o];
    const int r0 = blockIdx.x*16;
    for (int i=0;i<4;i++){
        const size_t r = (size_t)r0 + w*4 + i;
        __syncthreads();
        for (int m=o;m<320;m+=64){
            float yy = b2f(yv[r*320+m]);
            int h = m/KNN;
            sy2[w][m] = lrelu(bn1_a[h]*yy + bn1_c[h]);
        }
        __syncthreads();
        float best = -1e30f;
        for (int k=0;k<KNN;k++){
            float rv = b2f(rf[r*1280 + k*64 + o]);
            float lv = 0.f;
            #pragma unroll
            for (int h=0;h<16;h++) lv += wlr[h]*sy2[w][h*KNN+k];
            float val = lrelu(la*lv + lc + ra*rv + rc);
            best = fmaxf(best, val);
        }
        sout[o][w*4+i] = best;
    }
    __syncthreads();
    const int b = r0 >> 12, n0 = r0 & 4095;
    for (int m=tid;m<1024;m+=256){
        int oo = m >> 4, ii = m & 15;
        out[((size_t)b*64+oo)*NN + n0 + ii] = sout[oo][ii];
    }
}

extern "C" void kernel_launch(void* const* d_in, const int* in_sizes, int n_in,
                              void* d_out, int out_size, void* d_ws, size_t ws_size,
                              hipStream_t stream)
{
    const float* pts   = (const float*)d_in[0];
    const float* feat  = (const float*)d_in[1];
    const int*   idx   = (const int*)d_in[2];
    const float* wefp  = (const float*)d_in[3];
    const float* weff  = (const float*)d_in[4];
    const float* wq    = (const float*)d_in[5];
    const float* gq    = (const float*)d_in[6];
    const float* bq    = (const float*)d_in[7];
    const float* wpos1 = (const float*)d_in[8];
    const float* gp    = (const float*)d_in[9];
    const float* bp    = (const float*)d_in[10];
    const float* wpos2 = (const float*)d_in[11];
    const float* wattn = (const float*)d_in[12];
    const float* g1    = (const float*)d_in[13];
    const float* b1    = (const float*)d_in[14];
    const float* wl    = (const float*)d_in[15];
    const float* gl    = (const float*)d_in[16];
    const float* bl    = (const float*)d_in[17];
    const float* wres  = (const float*)d_in[18];
    const float* gr    = (const float*)d_in[19];
    const float* br    = (const float*)d_in[20];
    float* out = (float*)d_out;

    char* ws = (char*)d_ws;
    size_t o_ft16 = 0;
    size_t o_pt4  = o_ft16 + (size_t)NPTS*32*2;
    size_t o_qp16 = o_pt4  + (size_t)NPTS*4*4;
    size_t o_pp   = o_qp16 + (size_t)NPTS*64*2;
    size_t o_b16  = o_pp   + (size_t)NPTS*8*4;
    size_t o_bpp  = o_b16  + (size_t)NPTS*64*2;
    size_t o_packW= o_bpp  + (size_t)NPTS*8*4;
    size_t o_wdiff= o_packW + 24*512*2;
    size_t o_w32  = o_wdiff + 2048*4;
    size_t o_st   = o_w32   + 64*4;
    size_t o_qsum  = o_st;
    size_t o_qsq   = o_qsum + 64*4;
    size_t o_psum  = o_qsq  + 64*4;
    size_t o_psq   = o_psum + 8*4;
    size_t o_yslot = o_psq  + 8*4;
    size_t o_rslot = o_yslot + (size_t)64*32*4;
    size_t o_lslot = o_rslot + (size_t)64*128*4;
    size_t zero_bytes = (o_lslot + (size_t)256*128*4) - o_st;
    size_t o_par   = o_st + zero_bytes;
    size_t o_bnq_a = o_par;
    size_t o_bnq_c = o_bnq_a + 64*4;
    size_t o_bnp_a = o_bnq_c + 64*4;
    size_t o_bnp_c = o_bnp_a + 8*4;
    size_t o_bn1_a = o_bnp_c + 8*4;
    size_t o_bn1_c = o_bn1_a + 16*4;
    size_t o_bnl_a = o_bn1_c + 16*4;
    size_t o_bnl_c = o_bnl_a + 64*4;
    size_t o_bnr_a = o_bnl_c + 64*4;
    size_t o_bnr_c = o_bnr_a + 64*4;
    size_t o_yv = (o_bnr_c + 64*4 + 255) & ~(size_t)255;
    size_t o_rf = o_yv + (size_t)NPTS*320*2;

    unsigned short* ft16 = (unsigned short*)(ws + o_ft16);
    float* pt4  = (float*)(ws + o_pt4);
    unsigned short* qp16 = (unsigned short*)(ws + o_qp16);
    float* ppb  = (float*)(ws + o_pp);
    unsigned short* b16p = (unsigned short*)(ws + o_b16);
    float* bpp  = (float*)(ws + o_bpp);
    unsigned short* packW = (unsigned short*)(ws + o_packW);
    float* wdiff= (float*)(ws + o_wdiff);
    float* w32t = (float*)(ws + o_w32);
    float* qsum = (float*)(ws + o_qsum);
    float* qsq  = (float*)(ws + o_qsq);
    float* psum = (float*)(ws + o_psum);
    float* psq  = (float*)(ws + o_psq);
    float* yslot= (float*)(ws + o_yslot);
    float* rslot= (float*)(ws + o_rslot);
    float* lslot= (float*)(ws + o_lslot);
    float* bnq_a= (float*)(ws + o_bnq_a);
    float* bnq_c= (float*)(ws + o_bnq_c);
    float* bnp_a= (float*)(ws + o_bnp_a);
    float* bnp_c= (float*)(ws + o_bnp_c);
    float* bn1_a= (float*)(ws + o_bn1_a);
    float* bn1_c= (float*)(ws + o_bn1_c);
    float* bnl_a= (float*)(ws + o_bnl_a);
    float* bnl_c= (float*)(ws + o_bnl_c);
    float* bnr_a= (float*)(ws + o_bnr_a);
    float* bnr_c= (float*)(ws + o_bnr_c);
    unsigned short* yvp = (unsigned short*)(ws + o_yv);
    unsigned short* rfp = (unsigned short*)(ws + o_rf);

    hipMemsetAsync(ws + o_st, 0, zero_bytes, stream);

    kprep<<<1, 256, 0, stream>>>(weff, wattn, wres, packW, wdiff, w32t);
    k0_prep<<<128, 256, 0, stream>>>(pts, feat, wq, wpos1, wefp, wdiff,
                                     ft16, pt4, qp16, ppb, b16p, bpp,
                                     qsum, qsq, psum, psq);
    k1_paramsA<<<1, 64, 0, stream>>>(qsum, qsq, psum, psq, gq, bq, gp, bp,
                                     bnq_a, bnq_c, bnp_a, bnp_c);
    k2_main<<<NPTS/(4*PPW), 256, 0, stream>>>(ft16, pt4, qp16, ppb, b16p, bpp, idx,
                                     wefp, wpos2, packW, w32t,
                                     bnq_a, bnq_c, bnp_a, bnp_c,
                                     yvp, rfp, yslot, rslot);
    k3_paramsB<<<1, 128, 0, stream>>>(yslot, rslot, g1, b1, gr, br,
                                      bn1_a, bn1_c, bnr_a, bnr_c);
    k4_linstats<<<2048, 64, 0, stream>>>(yvp, bn1_a, bn1_c, wl, lslot);
    k5_paramsC<<<1, 128, 0, stream>>>(lslot, gl, bl, bnl_a, bnl_c);
    k6_final<<<2048, 256, 0, stream>>>(yvp, rfp, bn1_a, bn1_c, wl,
                                       bnl_a, bnl_c, bnr_a, bnr_c, out);
}